// Round 11
// baseline (138.147 us; speedup 1.0000x reference)
//
#include <hip/hip_runtime.h>
#include <hip/hip_bf16.h>

#define N_NODES 500000
#define N_FEAT 125
#define HID 128
#define OUTD 64
#define N_GRAPHS 4096
#define N_TYPES 100
#define NPAIRS 7813   /* ceil(500000/64); pairs 0..7811 = 64 nodes, pair 7812 = 32 nodes */
#define NBLOCKS 256   /* 1 block/CU; occupancy reg-capped at 2 waves/SIMD (R2-R9) */
#define NWAVES 8
#define TPAD 132      /* f32 T row stride: 132 mod 32 = 4 -> rows spread over banks */

typedef float f32x4 __attribute__((ext_vector_type(4)));
typedef short s16x4 __attribute__((ext_vector_type(4)));

// LDS layout (bytes) — T(f32) + W2(K16 A-frags) + W3(K16 A-frags) + bias2.
#define OFF_T 0
#define SZ_T (N_TYPES * TPAD * 4)                  // 52800
#define OFF_W2K (OFF_T + SZ_T)                     // 52800
#define SZ_W2K (8 * 8 * 64 * 8)                    // 32768
#define OFF_W3K (OFF_W2K + SZ_W2K)                 // 85568
#define SZ_W3K (4 * 8 * 64 * 8)                    // 16384
#define OFF_B2 (OFF_W3K + SZ_W3K)                  // 101952
#define LDS_BYTES (OFF_B2 + HID * 4)               // 102464 (1 block/CU)

// ws layout (bytes)
#define WS_GSUM 0
#define WS_GCNT ((size_t)N_GRAPHS * OUTD * 4)      // 1048576
#define WS_T    (WS_GCNT + (size_t)N_GRAPHS * 4)   // 1064960 (T as f32 now: 51200 B)
#define WS_ZERO WS_T                               // bytes zeroed (gsum+gcnt)
#define WS_ZERO_V4 (WS_ZERO / 16)                  // 66560 f32x4

__device__ __forceinline__ unsigned short f2bf(float f) {
  union { float f; unsigned u; } v; v.f = f;
  unsigned r = v.u + 0x7FFFu + ((v.u >> 16) & 1u);  // RNE
  return (unsigned short)(r >> 16);
}
__device__ __forceinline__ unsigned pk2bf(float a, float b) {
  __hip_bfloat162 h = __float22bfloat162_rn(float2{a, b});   // .x -> low 16, .y -> high 16
  union { __hip_bfloat162 h; unsigned u; } v; v.h = h;
  return v.u;
}
__device__ __forceinline__ s16x4 u2frag(uint2 v) {
  union { uint2 u; s16x4 s; } c; c.u = v; return c.s;
}

// ---- pre-pass: T[100][128] = emb @ W1[3:,:] + b1 (kept f32) + zero gsum/gcnt ----
extern "C" __global__ void gnn_prep(const float* __restrict__ emb,
                                    const float* __restrict__ W1,
                                    const float* __restrict__ b1,
                                    float* __restrict__ Tgf,
                                    f32x4* __restrict__ wsz)
{
  const int j = threadIdx.x;                       // 256 blocks x 128 threads
  const int tid = blockIdx.x * 128 + j;
  for (int i = tid; i < WS_ZERO_V4; i += 256 * 128)
    wsz[i] = (f32x4){0.f, 0.f, 0.f, 0.f};
  const int g = blockIdx.x;
  if (g < N_TYPES) {
    float acc = b1[j];
    const float* er = emb + g * N_FEAT;
    for (int k = 0; k < N_FEAT; ++k)
      acc = fmaf(er[k], W1[(3 + k) * HID + j], acc);   // W1 read coalesced over j
    Tgf[g * HID + j] = acc;                        // f32: feeds MFMA C operand directly
  }
}

extern "C" __global__ void __launch_bounds__(512, 2)
gnn_main(const float* __restrict__ pos, const int* __restrict__ z,
         const int* __restrict__ batch, const float* __restrict__ Tgf,
         const float* __restrict__ W1, const float* __restrict__ W2,
         const float* __restrict__ b2, const float* __restrict__ W3,
         float* __restrict__ gsum, int* __restrict__ gcnt)
{
  extern __shared__ char lds[];
  float* Tl = (float*)(lds + OFF_T);
  uint2* w2k = (uint2*)(lds + OFF_W2K);
  uint2* w3k = (uint2*)(lds + OFF_W3K);
  float* bias2 = (float*)(lds + OFF_B2);

  const int t = threadIdx.x;

  // ---- stage once per block ----
  for (int i = t; i < N_TYPES * HID; i += 512) {   // T: f32, padded rows
    int g = i >> 7, f = i & 127;
    Tl[g * TPAD + f] = Tgf[i];
  }
  // W2 as per-lane K=16 A-fragments: idx = (oi*8+ki)*64 + lane.
  // lane(q,l): A[m=l][k=q*4+j] = W2[f=ki*16+q*4+j][o=oi*16+l]
  for (int i = t; i < 8 * 8 * 64; i += 512) {
    int oi = i >> 9, ki = (i >> 6) & 7, ln = i & 63;
    int q = ln >> 4, l = ln & 15;
    int f0 = ki * 16 + q * 4, o = oi * 16 + l;
    uint2 v;
    v.x = pk2bf(W2[(f0 + 0) * HID + o], W2[(f0 + 1) * HID + o]);
    v.y = pk2bf(W2[(f0 + 2) * HID + o], W2[(f0 + 3) * HID + o]);
    w2k[i] = v;
  }
  // W3 as per-lane K=16 A-fragments: idx = (ob*8+oi)*64 + lane.
  for (int i = t; i < 4 * 8 * 64; i += 512) {
    int ob = i >> 9, rest = i & 511;
    int oi = rest >> 6, ln = rest & 63;
    int q = ln >> 4, l = ln & 15;
    int f0 = oi * 16 + q * 4, o = ob * 16 + l;
    uint2 v;
    v.x = pk2bf(W3[(f0 + 0) * OUTD + o], W3[(f0 + 1) * OUTD + o]);
    v.y = pk2bf(W3[(f0 + 2) * OUTD + o], W3[(f0 + 3) * OUTD + o]);
    w3k[i] = v;
  }
  if (t < HID) bias2[t] = b2[t];

  const int wave = t >> 6, lane = t & 63, quad = lane >> 4, l15 = lane & 15;

  // ---- W1 pos-rows as K=16 A-fragments, tile-invariant, in registers (16) ----
  // lane(q,l15): A[m=l15][k=q*4+j] = W1[c=q*4+j][f=oi*16+l15]; only c<3 nonzero
  uint2 wa1[8];
  #pragma unroll
  for (int oi = 0; oi < 8; ++oi) {
    if (quad == 0) {
      const int f = oi * 16 + l15;
      unsigned lo = (unsigned)f2bf(W1[f]) | ((unsigned)f2bf(W1[HID + f]) << 16);
      unsigned hi = (unsigned)f2bf(W1[2 * HID + f]);
      wa1[oi] = uint2{lo, hi};
    } else {
      wa1[oi] = uint2{0u, 0u};
    }
  }

  __syncthreads();   // the ONLY block-wide barrier

  const int gwave = blockIdx.x * NWAVES + wave;

  // 64 nodes/iter (R10).  Layer 1 moved to the MATRIX pipe: h1 strip =
  // mfma_16x16x16(A=W1pos, B=pos_bf16, C=T[z] gathered f32) -> C layout is
  // already the K16 B-fragment for layer 2 (R7 identity) -> layers 2,3 are
  // K16 MFMA chains.  VALU keeps only relu+pack epilogues + pool.
  for (int pair = gwave; pair < NPAIRS; pair += NBLOCKS * NWAVES) {
    const int base = pair * 64;
    const bool has2 = (pair != NPAIRS - 1);        // last pair: only 32 real nodes

    int id0 = batch[base + l15];
    int id1 = batch[base + 16 + l15];
    int id2 = -1, id3 = -1;
    if (has2) {
      id2 = batch[base + 32 + l15];
      id3 = batch[base + 48 + l15];
    }

    // per-m: T row offset + packed-bf16 pos B-fragment (quad 0 holds k=0..2)
    int Toff[4];
    uint2 bpos[4];
    #pragma unroll
    for (int m = 0; m < 4; ++m) {
      int node = base + m * 16 + l15;
      node = node < N_NODES ? node : N_NODES - 1;  // clamp fake half of last pair
      Toff[m] = z[node] * TPAD + quad * 4;
      const float px = pos[node * 3], py = pos[node * 3 + 1], pz = pos[node * 3 + 2];
      bpos[m] = (quad == 0) ? uint2{pk2bf(px, py), pk2bf(pz, 0.f)} : uint2{0u, 0u};
    }

    // ---- layer 1 on the matrix pipe + relu/pack epilogue ----
    uint2 a16[8][4];                               // K16 B-frags of h1 (per ki strip)
    __builtin_amdgcn_s_setprio(1);
    #pragma unroll
    for (int oi = 0; oi < 8; ++oi)
      #pragma unroll
      for (int m = 0; m < 4; ++m) {
        f32x4 cc = *(const f32x4*)(Tl + Toff[m] + oi * 16);   // T[z] gather = C input
        cc = __builtin_amdgcn_mfma_f32_16x16x16bf16_1k(
            u2frag(wa1[oi]), u2frag(bpos[m]), cc, 0, 0, 0);
        a16[oi][m].x = pk2bf(fmaxf(cc[0], 0.f), fmaxf(cc[1], 0.f));
        a16[oi][m].y = pk2bf(fmaxf(cc[2], 0.f), fmaxf(cc[3], 0.f));
      }
    __builtin_amdgcn_s_setprio(0);

    // ---- layer 2: K16 MFMA chain, b2 folded into accumulator init ----
    uint2 pb[8][4];
    __builtin_amdgcn_s_setprio(1);
    #pragma unroll
    for (int oi = 0; oi < 8; ++oi) {
      f32x4 bv = *(const f32x4*)(bias2 + oi * 16 + quad * 4);
      f32x4 c[4] = {bv, bv, bv, bv};
      #pragma unroll
      for (int ki = 0; ki < 8; ++ki) {
        s16x4 wa = u2frag(w2k[(oi * 8 + ki) * 64 + lane]);
        #pragma unroll
        for (int m = 0; m < 4; ++m)
          c[m] = __builtin_amdgcn_mfma_f32_16x16x16bf16_1k(
              wa, u2frag(a16[ki][m]), c[m], 0, 0, 0);
      }
      #pragma unroll
      for (int m = 0; m < 4; ++m) {
        pb[oi][m].x = pk2bf(fmaxf(c[m][0], 0.f), fmaxf(c[m][1], 0.f));
        pb[oi][m].y = pk2bf(fmaxf(c[m][2], 0.f), fmaxf(c[m][3], 0.f));
      }
    }
    __builtin_amdgcn_s_setprio(0);

    // ---- layer 3: K16 MFMA chain (w3k A-frags) ----
    f32x4 acc3[4][4] = {};
    __builtin_amdgcn_s_setprio(1);
    #pragma unroll
    for (int ob = 0; ob < 4; ++ob)
      #pragma unroll
      for (int oi = 0; oi < 8; ++oi) {
        s16x4 wa = u2frag(w3k[(ob * 8 + oi) * 64 + lane]);
        #pragma unroll
        for (int m = 0; m < 4; ++m)
          acc3[ob][m] = __builtin_amdgcn_mfma_f32_16x16x16bf16_1k(
              wa, u2frag(pb[oi][m]), acc3[ob][m], 0, 0, 0);
      }
    __builtin_amdgcn_s_setprio(0);

    // ---- pool: in-register segmented reduce over up to 64 sorted columns ----
    // acc3[ob][m]: row(out-dim)=ob*16+quad*4+r, col(node)=l15+16m.
    {
      const int NT = has2 ? 64 : 32;
      int done = 0;
      while (done < NT) {                          // wave-uniform loop
        const int sel = done >> 4;
        int srcv = (sel & 2) ? ((sel & 1) ? id3 : id2)
                             : ((sel & 1) ? id1 : id0);
        const int g = __builtin_amdgcn_readlane(srcv, done & 15);
        const bool m0 = (id0 == g), m1 = (id1 == g), m2 = (id2 == g), m3 = (id3 == g);
        float red[4][4];
        #pragma unroll
        for (int ob = 0; ob < 4; ++ob)
          #pragma unroll
          for (int r = 0; r < 4; ++r)
            red[ob][r] = (m0 ? acc3[ob][0][r] : 0.f) + (m1 ? acc3[ob][1][r] : 0.f)
                       + (m2 ? acc3[ob][2][r] : 0.f) + (m3 ? acc3[ob][3][r] : 0.f);
        #pragma unroll
        for (int s = 1; s <= 8; s <<= 1)
          #pragma unroll
          for (int ob = 0; ob < 4; ++ob)
            #pragma unroll
            for (int r = 0; r < 4; ++r)
              red[ob][r] += __shfl_xor(red[ob][r], s, 64);
        const int cnt = (int)((__popcll(__ballot(m0)) + __popcll(__ballot(m1)) +
                               __popcll(__ballot(m2)) + __popcll(__ballot(m3))) >> 2);
        if (l15 == 0) {                            // 4 lanes (one per quad) fire atomics
          #pragma unroll
          for (int ob = 0; ob < 4; ++ob)
            #pragma unroll
            for (int r = 0; r < 4; ++r)
              atomicAdd(&gsum[g * OUTD + ob * 16 + quad * 4 + r], red[ob][r]);
        }
        if (lane == 0) atomicAdd(&gcnt[g], cnt);
        done += cnt;                               // cnt >= 1: column `done` matches g
      }
    }
  }
}

extern "C" __global__ void gnn_finalize(const float* __restrict__ gsum,
                                        const int* __restrict__ gcnt,
                                        const float* __restrict__ b3,
                                        float* __restrict__ out)
{
  int i = blockIdx.x * 256 + threadIdx.x;
  if (i < N_GRAPHS * OUTD) {
    int g = i >> 6, o = i & 63;
    int c = gcnt[g];
    out[i] = (c > 0) ? (gsum[i] / (float)c + b3[o]) : 0.f;
  }
}

extern "C" void kernel_launch(void* const* d_in, const int* in_sizes, int n_in,
                              void* d_out, int out_size, void* d_ws, size_t ws_size,
                              hipStream_t stream) {
  const float* pos  = (const float*)d_in[0];
  const int*   z    = (const int*)d_in[1];
  const int*   batch= (const int*)d_in[2];
  const float* emb  = (const float*)d_in[3];
  const float* W1   = (const float*)d_in[4];
  const float* b1   = (const float*)d_in[5];
  const float* W2   = (const float*)d_in[6];
  const float* b2   = (const float*)d_in[7];
  const float* W3   = (const float*)d_in[8];
  const float* b3   = (const float*)d_in[9];

  float* gsum = (float*)d_ws;
  int*   gcnt = (int*)((char*)d_ws + WS_GCNT);
  float* Tgf  = (float*)((char*)d_ws + WS_T);

  // prep also zeroes gsum/gcnt (memset dispatch folded in)
  hipLaunchKernelGGL(gnn_prep, dim3(256), dim3(HID), 0, stream,
                     emb, W1, b1, Tgf, (f32x4*)d_ws);

  hipFuncSetAttribute((const void*)gnn_main,
                      hipFuncAttributeMaxDynamicSharedMemorySize, LDS_BYTES);
  hipLaunchKernelGGL(gnn_main, dim3(NBLOCKS), dim3(512), LDS_BYTES, stream,
                     pos, z, batch, Tgf, W1, W2, b2, W3, gsum, gcnt);
  hipLaunchKernelGGL(gnn_finalize, dim3((N_GRAPHS * OUTD + 255) / 256), dim3(256), 0, stream,
                     gsum, gcnt, b3, (float*)d_out);
}

// Round 12
// 135.853 us; speedup vs baseline: 1.0169x; 1.0169x over previous
//
#include <hip/hip_runtime.h>
#include <hip/hip_bf16.h>

#define N_NODES 500000
#define N_FEAT 125
#define HID 128
#define OUTD 64
#define N_GRAPHS 4096
#define N_TYPES 100
#define NPAIRS 7813   /* ceil(500000/64); pairs 0..7811 = 64 nodes, pair 7812 = 32 nodes */
#define NBLOCKS 256   /* 1 block/CU; occupancy reg-capped at 2 waves/SIMD (R2-R9) */
#define NWAVES 8
#define TPAD 132      /* f32 T row stride: 132 mod 32 = 4 -> rows spread over banks */
#define WPAD 136      /* bf16 row stride for w2t (R1-R10 proven) */

typedef float f32x4 __attribute__((ext_vector_type(4)));
typedef short s16x8 __attribute__((ext_vector_type(8)));
typedef short s16x4 __attribute__((ext_vector_type(4)));

// LDS layout (bytes) — T(f32) + W2 rows (K32 path) + W3 K16 A-frags + bias2.
#define OFF_T 0
#define SZ_T (N_TYPES * TPAD * 4)                  // 52800
#define OFF_W2 (OFF_T + SZ_T)                      // 52800
#define SZ_W2 (HID * WPAD * 2)                     // 34816
#define OFF_W3K (OFF_W2 + SZ_W2)                   // 87616
#define SZ_W3K (4 * 8 * 64 * 8)                    // 16384
#define OFF_B2 (OFF_W3K + SZ_W3K)                  // 104000
#define LDS_BYTES (OFF_B2 + HID * 4)               // 104512 (1 block/CU)

// ws layout (bytes)
#define WS_GSUM 0
#define WS_GCNT ((size_t)N_GRAPHS * OUTD * 4)      // 1048576
#define WS_T    (WS_GCNT + (size_t)N_GRAPHS * 4)   // 1064960 (T as f32: 51200 B)
#define WS_ZERO WS_T                               // bytes zeroed (gsum+gcnt)
#define WS_ZERO_V4 (WS_ZERO / 16)                  // 66560 f32x4

__device__ __forceinline__ unsigned short f2bf(float f) {
  union { float f; unsigned u; } v; v.f = f;
  unsigned r = v.u + 0x7FFFu + ((v.u >> 16) & 1u);  // RNE
  return (unsigned short)(r >> 16);
}
__device__ __forceinline__ unsigned pk2bf(float a, float b) {
  __hip_bfloat162 h = __float22bfloat162_rn(float2{a, b});   // .x -> low 16, .y -> high 16
  union { __hip_bfloat162 h; unsigned u; } v; v.h = h;
  return v.u;
}
__device__ __forceinline__ s16x4 u2frag(uint2 v) {
  union { uint2 u; s16x4 s; } c; c.u = v; return c.s;
}

// ---- pre-pass: T[100][128] = emb @ W1[3:,:] + b1 (f32 out) + zero gsum/gcnt ----
extern "C" __global__ void gnn_prep(const float* __restrict__ emb,
                                    const float* __restrict__ W1,
                                    const float* __restrict__ b1,
                                    float* __restrict__ Tgf,
                                    f32x4* __restrict__ wsz)
{
  const int j = threadIdx.x;                       // 256 blocks x 128 threads
  const int tid = blockIdx.x * 128 + j;
  for (int i = tid; i < WS_ZERO_V4; i += 256 * 128)
    wsz[i] = (f32x4){0.f, 0.f, 0.f, 0.f};
  const int g = blockIdx.x;
  if (g < N_TYPES) {
    float acc = b1[j];
    const float* er = emb + g * N_FEAT;
    for (int k = 0; k < N_FEAT; ++k)
      acc = fmaf(er[k], W1[(3 + k) * HID + j], acc);   // W1 read coalesced over j
    Tgf[g * HID + j] = acc;                        // f32: feeds MFMA C operand directly
  }
}

extern "C" __global__ void __launch_bounds__(512, 2)
gnn_main(const float* __restrict__ pos, const int* __restrict__ z,
         const int* __restrict__ batch, const float* __restrict__ Tgf,
         const float* __restrict__ W1, const float* __restrict__ W2,
         const float* __restrict__ b2, const float* __restrict__ W3,
         float* __restrict__ gsum, int* __restrict__ gcnt)
{
  extern __shared__ char lds[];
  float* Tl = (float*)(lds + OFF_T);
  unsigned short* w2t = (unsigned short*)(lds + OFF_W2);
  uint2* w3k = (uint2*)(lds + OFF_W3K);
  float* bias2 = (float*)(lds + OFF_B2);

  const int t = threadIdx.x;

  // ---- stage once per block ----
  for (int i = t; i < N_TYPES * HID; i += 512) {   // T: f32, padded rows
    int g = i >> 7, f = i & 127;
    Tl[g * TPAD + f] = Tgf[i];
  }
  for (int i = t; i < HID * HID; i += 512) {       // W2^T [n][k] bf16 (K32 path)
    int k = i >> 7, n = i & 127;
    w2t[n * WPAD + k] = f2bf(W2[i]);
  }
  // W3 as per-lane K=16 A-fragments: idx = (ob*8+oi)*64 + lane.
  for (int i = t; i < 4 * 8 * 64; i += 512) {
    int ob = i >> 9, rest = i & 511;
    int oi = rest >> 6, ln = rest & 63;
    int q = ln >> 4, l = ln & 15;
    int f0 = oi * 16 + q * 4, o = ob * 16 + l;
    uint2 v;
    v.x = pk2bf(W3[(f0 + 0) * OUTD + o], W3[(f0 + 1) * OUTD + o]);
    v.y = pk2bf(W3[(f0 + 2) * OUTD + o], W3[(f0 + 3) * OUTD + o]);
    w3k[i] = v;
  }
  if (t < HID) bias2[t] = b2[t];

  const int wave = t >> 6, lane = t & 63, quad = lane >> 4, l15 = lane & 15;
  const bool hi32 = (lane >= 32);
  // bpermute pull addresses for the C->K32-B transpose (R5/R6 verified):
  // src lane = 16*(2*(q&1) + (j2>>1)) + l15
  const int A0 = ((((lane >> 4) & 1) << 5) + l15) << 2;
  const int A1 = A0 + 64;

  // ---- W1 pos-rows as K=16 A-fragments, tile-invariant, in registers (16) ----
  // lane(q,l15): A[m=l15][k=q*4+j] = W1[c=q*4+j][f=oi*16+l15]; only c<3 nonzero
  uint2 wa1[8];
  #pragma unroll
  for (int oi = 0; oi < 8; ++oi) {
    if (quad == 0) {
      const int f = oi * 16 + l15;
      unsigned lo = (unsigned)f2bf(W1[f]) | ((unsigned)f2bf(W1[HID + f]) << 16);
      unsigned hi = (unsigned)f2bf(W1[2 * HID + f]);
      wa1[oi] = uint2{lo, hi};
    } else {
      wa1[oi] = uint2{0u, 0u};
    }
  }

  __syncthreads();   // the ONLY block-wide barrier

  const int gwave = blockIdx.x * NWAVES + wave;

  // 64 nodes/iter.  Layer 1 on the MATRIX pipe (R11, verified) -> packed C
  // strips -> R5/R6 bpermute transpose (verified) -> K32 layer 2 (R10,
  // cycle-efficient) -> K16 layer 3 (R10) -> in-register pool (R10).
  for (int pair = gwave; pair < NPAIRS; pair += NBLOCKS * NWAVES) {
    const int base = pair * 64;
    const bool has2 = (pair != NPAIRS - 1);        // last pair: only 32 real nodes

    int id0 = batch[base + l15];
    int id1 = batch[base + 16 + l15];
    int id2 = -1, id3 = -1;
    if (has2) {
      id2 = batch[base + 32 + l15];
      id3 = batch[base + 48 + l15];
    }

    // per-m: T row offset + packed-bf16 pos B-fragment (quad 0 holds k=0..2)
    int Toff[4];
    uint2 bpos[4];
    #pragma unroll
    for (int m = 0; m < 4; ++m) {
      int node = base + m * 16 + l15;
      node = node < N_NODES ? node : N_NODES - 1;  // clamp fake half of last pair
      Toff[m] = z[node] * TPAD + quad * 4;
      const float px = pos[node * 3], py = pos[node * 3 + 1], pz = pos[node * 3 + 2];
      bpos[m] = (quad == 0) ? uint2{pk2bf(px, py), pk2bf(pz, 0.f)} : uint2{0u, 0u};
    }

    // ---- layer 1 on matrix pipe + relu/pack + fused per-pair bperm transpose ----
    // Strip pair (2kb,2kb+1): mfma(A=W1pos, B=pos, C=T[z]) -> pack (=R5's Pp
    // format) -> 16 bperm -> an[m][kb] = K32 B-fragment of h1.
    s16x8 an[4][4];
    __builtin_amdgcn_s_setprio(1);
    #pragma unroll
    for (int kb = 0; kb < 4; ++kb) {
      uint2 Ps[2][4];                              // [strip of pair][m]
      #pragma unroll
      for (int s = 0; s < 2; ++s) {
        const int oi = 2 * kb + s;
        #pragma unroll
        for (int m = 0; m < 4; ++m) {
          f32x4 cc = *(const f32x4*)(Tl + Toff[m] + oi * 16);   // T[z] gather = C in
          cc = __builtin_amdgcn_mfma_f32_16x16x16bf16_1k(
              u2frag(wa1[oi]), u2frag(bpos[m]), cc, 0, 0, 0);
          Ps[s][m].x = pk2bf(fmaxf(cc[0], 0.f), fmaxf(cc[1], 0.f));
          Ps[s][m].y = pk2bf(fmaxf(cc[2], 0.f), fmaxf(cc[3], 0.f));
        }
      }
      // an[m][kb].dw[j2] = Ps[q>>1][m].d(j2&1) from lane (2(q&1)+(j2>>1), l15)
      #pragma unroll
      for (int m = 0; m < 4; ++m) {
        s16x8 fr;
        #pragma unroll
        for (int j2 = 0; j2 < 4; ++j2) {
          const int addr = (j2 < 2) ? A0 : A1;
          int t0 = __builtin_amdgcn_ds_bpermute(addr, (int)((j2 & 1) ? Ps[0][m].y : Ps[0][m].x));
          int t1 = __builtin_amdgcn_ds_bpermute(addr, (int)((j2 & 1) ? Ps[1][m].y : Ps[1][m].x));
          ((int*)&fr)[j2] = hi32 ? t1 : t0;
        }
        an[m][kb] = fr;
      }
    }
    __builtin_amdgcn_s_setprio(0);

    // ---- layer 2: K32 MFMA chain (cycle-efficient), b2 folded into C init ----
    // C-layout lane(q,l15): f = oi*16+q*4+r, node = l15+16m -> packed output is
    // the K16 B-fragment for layer 3 (R7 identity).
    uint2 pb[8][4];
    __builtin_amdgcn_s_setprio(1);
    #pragma unroll
    for (int oi = 0; oi < 8; ++oi) {
      f32x4 bv = *(const f32x4*)(bias2 + oi * 16 + quad * 4);
      f32x4 c[4] = {bv, bv, bv, bv};
      #pragma unroll
      for (int k = 0; k < 4; ++k) {
        s16x8 w = *(const s16x8*)(w2t + (oi * 16 + l15) * WPAD + k * 32 + quad * 8);
        #pragma unroll
        for (int m = 0; m < 4; ++m)
          c[m] = __builtin_amdgcn_mfma_f32_16x16x32_bf16(w, an[m][k], c[m], 0, 0, 0);
      }
      #pragma unroll
      for (int m = 0; m < 4; ++m) {
        pb[oi][m].x = pk2bf(fmaxf(c[m][0], 0.f), fmaxf(c[m][1], 0.f));
        pb[oi][m].y = pk2bf(fmaxf(c[m][2], 0.f), fmaxf(c[m][3], 0.f));
      }
    }
    __builtin_amdgcn_s_setprio(0);

    // ---- layer 3: K16 MFMA chain (w3k A-frags) ----
    f32x4 acc3[4][4] = {};
    __builtin_amdgcn_s_setprio(1);
    #pragma unroll
    for (int ob = 0; ob < 4; ++ob)
      #pragma unroll
      for (int oi = 0; oi < 8; ++oi) {
        s16x4 wa = u2frag(w3k[(ob * 8 + oi) * 64 + lane]);
        #pragma unroll
        for (int m = 0; m < 4; ++m)
          acc3[ob][m] = __builtin_amdgcn_mfma_f32_16x16x16bf16_1k(
              wa, u2frag(pb[oi][m]), acc3[ob][m], 0, 0, 0);
      }
    __builtin_amdgcn_s_setprio(0);

    // ---- pool: in-register segmented reduce over up to 64 sorted columns ----
    // acc3[ob][m]: row(out-dim)=ob*16+quad*4+r, col(node)=l15+16m.
    {
      const int NT = has2 ? 64 : 32;
      int done = 0;
      while (done < NT) {                          // wave-uniform loop
        const int sel = done >> 4;
        int srcv = (sel & 2) ? ((sel & 1) ? id3 : id2)
                             : ((sel & 1) ? id1 : id0);
        const int g = __builtin_amdgcn_readlane(srcv, done & 15);
        const bool m0 = (id0 == g), m1 = (id1 == g), m2 = (id2 == g), m3 = (id3 == g);
        float red[4][4];
        #pragma unroll
        for (int ob = 0; ob < 4; ++ob)
          #pragma unroll
          for (int r = 0; r < 4; ++r)
            red[ob][r] = (m0 ? acc3[ob][0][r] : 0.f) + (m1 ? acc3[ob][1][r] : 0.f)
                       + (m2 ? acc3[ob][2][r] : 0.f) + (m3 ? acc3[ob][3][r] : 0.f);
        #pragma unroll
        for (int s = 1; s <= 8; s <<= 1)
          #pragma unroll
          for (int ob = 0; ob < 4; ++ob)
            #pragma unroll
            for (int r = 0; r < 4; ++r)
              red[ob][r] += __shfl_xor(red[ob][r], s, 64);
        const int cnt = (int)((__popcll(__ballot(m0)) + __popcll(__ballot(m1)) +
                               __popcll(__ballot(m2)) + __popcll(__ballot(m3))) >> 2);
        if (l15 == 0) {                            // 4 lanes (one per quad) fire atomics
          #pragma unroll
          for (int ob = 0; ob < 4; ++ob)
            #pragma unroll
            for (int r = 0; r < 4; ++r)
              atomicAdd(&gsum[g * OUTD + ob * 16 + quad * 4 + r], red[ob][r]);
        }
        if (lane == 0) atomicAdd(&gcnt[g], cnt);
        done += cnt;                               // cnt >= 1: column `done` matches g
      }
    }
  }
}

extern "C" __global__ void gnn_finalize(const float* __restrict__ gsum,
                                        const int* __restrict__ gcnt,
                                        const float* __restrict__ b3,
                                        float* __restrict__ out)
{
  int i = blockIdx.x * 256 + threadIdx.x;
  if (i < N_GRAPHS * OUTD) {
    int g = i >> 6, o = i & 63;
    int c = gcnt[g];
    out[i] = (c > 0) ? (gsum[i] / (float)c + b3[o]) : 0.f;
  }
}

extern "C" void kernel_launch(void* const* d_in, const int* in_sizes, int n_in,
                              void* d_out, int out_size, void* d_ws, size_t ws_size,
                              hipStream_t stream) {
  const float* pos  = (const float*)d_in[0];
  const int*   z    = (const int*)d_in[1];
  const int*   batch= (const int*)d_in[2];
  const float* emb  = (const float*)d_in[3];
  const float* W1   = (const float*)d_in[4];
  const float* b1   = (const float*)d_in[5];
  const float* W2   = (const float*)d_in[6];
  const float* b2   = (const float*)d_in[7];
  const float* W3   = (const float*)d_in[8];
  const float* b3   = (const float*)d_in[9];

  float* gsum = (float*)d_ws;
  int*   gcnt = (int*)((char*)d_ws + WS_GCNT);
  float* Tgf  = (float*)((char*)d_ws + WS_T);

  // prep also zeroes gsum/gcnt (memset dispatch folded in)
  hipLaunchKernelGGL(gnn_prep, dim3(256), dim3(HID), 0, stream,
                     emb, W1, b1, Tgf, (f32x4*)d_ws);

  hipFuncSetAttribute((const void*)gnn_main,
                      hipFuncAttributeMaxDynamicSharedMemorySize, LDS_BYTES);
  hipLaunchKernelGGL(gnn_main, dim3(NBLOCKS), dim3(512), LDS_BYTES, stream,
                     pos, z, batch, Tgf, W1, W2, b2, W3, gsum, gcnt);
  hipLaunchKernelGGL(gnn_finalize, dim3((N_GRAPHS * OUTD + 255) / 256), dim3(256), 0, stream,
                     gsum, gcnt, b3, (float*)d_out);
}

// Round 13
// 133.751 us; speedup vs baseline: 1.0329x; 1.0157x over previous
//
#include <hip/hip_runtime.h>
#include <hip/hip_bf16.h>

#define N_NODES 500000
#define N_FEAT 125
#define HID 128
#define OUTD 64
#define N_GRAPHS 4096
#define N_TYPES 100
#define NPAIRS 7813   /* ceil(500000/64); pairs 0..7811 = 64 nodes, pair 7812 = 32 nodes */
#define NBLOCKS 256   /* 1 block/CU; occupancy reg-capped at 2 waves/SIMD (R2-R9) */
#define NWAVES 8
#define GSTRIDE (NBLOCKS * NWAVES)
#define WPAD 136      /* bf16 row stride: 16B-aligned; 68 dwords == 4 mod 32 banks */

typedef float f32x4 __attribute__((ext_vector_type(4)));
typedef short s16x8 __attribute__((ext_vector_type(8)));
typedef short s16x4 __attribute__((ext_vector_type(4)));

// LDS layout (bytes) — T + W2 + W3(K16 A-frags) + bias + W1 pos rows (R10).
#define OFF_T 0
#define SZ_T (N_TYPES * WPAD * 2)                  // 27200
#define OFF_W2 (OFF_T + SZ_T)                      // 27200
#define OFF_W3K (OFF_W2 + HID * WPAD * 2)          // 62016 (4 ob x 8 oi x 64 lanes x 8B)
#define OFF_B2 (OFF_W3K + 4 * 8 * 64 * 8)          // 78400
#define OFF_W1 (OFF_B2 + HID * 4)                  // 78912 (W1 pos rows, f32 3x128)
#define LDS_BYTES (OFF_W1 + 3 * HID * 4)           // 80448

// ws layout (bytes)
#define WS_GSUM 0
#define WS_GCNT ((size_t)N_GRAPHS * OUTD * 4)      // 1048576
#define WS_T    (WS_GCNT + (size_t)N_GRAPHS * 4)   // 1064960
#define WS_ZERO WS_T                               // bytes zeroed (gsum+gcnt)
#define WS_ZERO_V4 (WS_ZERO / 16)                  // 66560 f32x4

__device__ __forceinline__ unsigned short f2bf(float f) {
  union { float f; unsigned u; } v; v.f = f;
  unsigned r = v.u + 0x7FFFu + ((v.u >> 16) & 1u);  // RNE
  return (unsigned short)(r >> 16);
}
__device__ __forceinline__ float bf2f(unsigned short u) {
  union { unsigned u; float f; } v; v.u = ((unsigned)u) << 16;
  return v.f;
}
__device__ __forceinline__ unsigned pk2bf(float a, float b) {
  __hip_bfloat162 h = __float22bfloat162_rn(float2{a, b});   // .x -> low 16, .y -> high 16
  union { __hip_bfloat162 h; unsigned u; } v; v.h = h;
  return v.u;
}
__device__ __forceinline__ s16x4 u2frag(uint2 v) {
  union { uint2 u; s16x4 s; } c; c.u = v; return c.s;
}

// ---- pre-pass: T[100][128] = emb @ W1[3:,:] + b1 (fp32 math, bf16 store) ----
extern "C" __global__ void gnn_prep(const float* __restrict__ emb,
                                    const float* __restrict__ W1,
                                    const float* __restrict__ b1,
                                    unsigned short* __restrict__ Tg,
                                    f32x4* __restrict__ wsz)
{
  const int j = threadIdx.x;                       // 256 blocks x 128 threads
  const int tid = blockIdx.x * 128 + j;
  for (int i = tid; i < WS_ZERO_V4; i += 256 * 128)
    wsz[i] = (f32x4){0.f, 0.f, 0.f, 0.f};
  const int g = blockIdx.x;
  if (g < N_TYPES) {
    float acc = b1[j];
    const float* er = emb + g * N_FEAT;
    for (int k = 0; k < N_FEAT; ++k)
      acc = fmaf(er[k], W1[(3 + k) * HID + j], acc);   // W1 read coalesced over j
    Tg[g * HID + j] = f2bf(acc);
  }
}

extern "C" __global__ void __launch_bounds__(512, 2)
gnn_main(const float* __restrict__ pos, const int* __restrict__ z,
         const int* __restrict__ batch, const unsigned short* __restrict__ Tg,
         const float* __restrict__ W1, const float* __restrict__ W2,
         const float* __restrict__ b2, const float* __restrict__ W3,
         float* __restrict__ gsum, int* __restrict__ gcnt)
{
  extern __shared__ char lds[];
  unsigned short* Tl  = (unsigned short*)(lds + OFF_T);
  unsigned short* w2t = (unsigned short*)(lds + OFF_W2);
  uint2* w3k = (uint2*)(lds + OFF_W3K);
  float* bias2 = (float*)(lds + OFF_B2);
  float* w1l   = (float*)(lds + OFF_W1);

  const int t = threadIdx.x;

  // ---- stage once per block ----
  for (int i = t; i < N_TYPES * HID; i += 512) {   // T: bf16, padded rows
    int g = i >> 7, f = i & 127;
    Tl[g * WPAD + f] = Tg[i];
  }
  for (int i = t; i < HID * HID; i += 512) {       // W2^T [n][k] bf16
    int k = i >> 7, n = i & 127;
    w2t[n * WPAD + k] = f2bf(W2[i]);
  }
  // W3 as per-lane K=16 A-fragments: idx = (ob*8+oi)*64 + lane.
  for (int i = t; i < 4 * 8 * 64; i += 512) {
    int ob = i >> 9, rest = i & 511;
    int oi = rest >> 6, ln = rest & 63;
    int q = ln >> 4, l = ln & 15;
    int f0 = oi * 16 + q * 4, o = ob * 16 + l;
    uint2 v;
    v.x = pk2bf(W3[(f0 + 0) * OUTD + o], W3[(f0 + 1) * OUTD + o]);
    v.y = pk2bf(W3[(f0 + 2) * OUTD + o], W3[(f0 + 3) * OUTD + o]);
    w3k[i] = v;
  }
  if (t < HID) bias2[t] = b2[t];
  if (t < 3 * HID) w1l[t] = W1[t];                 // pos rows of W1, f32

  const int wave = t >> 6, lane = t & 63, quad = lane >> 4, l15 = lane & 15;

  __syncthreads();   // the ONLY block-wide barrier

  // ---- software-pipelined grid-stride loop over 64-node pairs (R10 body) ----
  // The kernel is LATENCY-bound at 2 waves/SIMD (R10-R12: pipe shuffling is
  // neutral; nothing saturated).  Next pair's batch/z/pos loads are issued at
  // the TOP of the current iteration so their ~200-500cy L2 latency hides
  // under this pair's ~4000cy of compute.  ~20 extra VGPRs (budget 256).
  int pair = blockIdx.x * NWAVES + wave;
  int cid0 = 0, cid1 = 0, cid2 = -1, cid3 = -1;
  int cz[4];
  float cpx[4], cpy[4], cpz[4];
  if (pair < NPAIRS) {
    const int base = pair * 64;
    const bool h2 = (pair != NPAIRS - 1);
    cid0 = batch[base + l15];
    cid1 = batch[base + 16 + l15];
    int a2 = base + 32 + l15, a3 = base + 48 + l15;
    a2 = a2 < N_NODES ? a2 : N_NODES - 1;          // OOB only when !h2
    a3 = a3 < N_NODES ? a3 : N_NODES - 1;
    cid2 = h2 ? batch[a2] : -1;
    cid3 = h2 ? batch[a3] : -1;
    #pragma unroll
    for (int m = 0; m < 4; ++m) {
      int node = base + m * 16 + l15;
      node = node < N_NODES ? node : N_NODES - 1;  // clamp fake half of last pair
      cz[m] = z[node];
      cpx[m] = pos[node * 3]; cpy[m] = pos[node * 3 + 1]; cpz[m] = pos[node * 3 + 2];
    }
  }

  while (pair < NPAIRS) {
    // ---- issue NEXT pair's global loads first (fire-and-forget) ----
    const int npair = pair + GSTRIDE;
    int nid0 = 0, nid1 = 0, nid2 = -1, nid3 = -1;
    int nz[4];
    float npx[4] = {}, npy[4] = {}, npz[4] = {};
    nz[0] = nz[1] = nz[2] = nz[3] = 0;
    if (npair < NPAIRS) {                          // wave-uniform branch
      const int nb = npair * 64;
      const bool nh2 = (npair != NPAIRS - 1);
      nid0 = batch[nb + l15];
      nid1 = batch[nb + 16 + l15];
      int a2 = nb + 32 + l15, a3 = nb + 48 + l15;
      a2 = a2 < N_NODES ? a2 : N_NODES - 1;
      a3 = a3 < N_NODES ? a3 : N_NODES - 1;
      nid2 = nh2 ? batch[a2] : -1;
      nid3 = nh2 ? batch[a3] : -1;
      #pragma unroll
      for (int m = 0; m < 4; ++m) {
        int node = nb + m * 16 + l15;
        node = node < N_NODES ? node : N_NODES - 1;
        nz[m] = z[node];
        npx[m] = pos[node * 3]; npy[m] = pos[node * 3 + 1]; npz[m] = pos[node * 3 + 2];
      }
    }

    const bool has2 = (pair != NPAIRS - 1);

    // ---- layer 1 in VALU, directly into MFMA B-fragments (x^T operand) ----
    // h1[node][f] = relu(T[z][f] + px*W1r0[f] + py*W1r1[f] + pz*W1r2[f])
    s16x8 a[4][4];
    {
      const unsigned short* Tr[4];
      #pragma unroll
      for (int m = 0; m < 4; ++m) Tr[m] = Tl + cz[m] * WPAD;
      #pragma unroll
      for (int k = 0; k < 4; ++k) {
        float w1s[3][8];                           // broadcast within quads
        #pragma unroll
        for (int c = 0; c < 3; ++c) {
          *(f32x4*)&w1s[c][0] = *(const f32x4*)(w1l + c * HID + k * 32 + quad * 8);
          *(f32x4*)&w1s[c][4] = *(const f32x4*)(w1l + c * HID + k * 32 + quad * 8 + 4);
        }
        #pragma unroll
        for (int m = 0; m < 4; ++m) {
          s16x8 tf = *(const s16x8*)(Tr[m] + k * 32 + quad * 8);
          s16x8 fr;
          #pragma unroll
          for (int j = 0; j < 8; j += 2) {
            float v0 = bf2f((unsigned short)tf[j])
                     + cpx[m] * w1s[0][j] + cpy[m] * w1s[1][j] + cpz[m] * w1s[2][j];
            float v1 = bf2f((unsigned short)tf[j + 1])
                     + cpx[m] * w1s[0][j + 1] + cpy[m] * w1s[1][j + 1] + cpz[m] * w1s[2][j + 1];
            ((unsigned*)&fr)[j >> 1] = pk2bf(fmaxf(v0, 0.f), fmaxf(v1, 0.f));
          }
          a[m][k] = fr;
        }
      }
    }

    // ---- layer 2 + fused epilogue: the packed C-strip IS a K=16 B-fragment ----
    uint2 pb[8][4];
    __builtin_amdgcn_s_setprio(1);
    #pragma unroll
    for (int oi = 0; oi < 8; ++oi) {
      f32x4 c[4] = {};
      #pragma unroll
      for (int k = 0; k < 4; ++k) {
        s16x8 w = *(const s16x8*)(w2t + (oi * 16 + l15) * WPAD + k * 32 + quad * 8);
        #pragma unroll
        for (int m = 0; m < 4; ++m)
          c[m] = __builtin_amdgcn_mfma_f32_16x16x32_bf16(w, a[m][k], c[m], 0, 0, 0);
      }
      const int f0 = oi * 16 + quad * 4;
      f32x4 bv = *(const f32x4*)(bias2 + f0);
      #pragma unroll
      for (int m = 0; m < 4; ++m) {
        pb[oi][m].x = pk2bf(fmaxf(c[m][0] + bv[0], 0.f), fmaxf(c[m][1] + bv[1], 0.f));
        pb[oi][m].y = pk2bf(fmaxf(c[m][2] + bv[2], 0.f), fmaxf(c[m][3] + bv[3], 0.f));
      }
    }
    __builtin_amdgcn_s_setprio(0);

    // ---- layer 3: mfma_f32_16x16x16_bf16, K-block = oi strip ----
    f32x4 acc3[4][4] = {};
    __builtin_amdgcn_s_setprio(1);
    #pragma unroll
    for (int ob = 0; ob < 4; ++ob)
      #pragma unroll
      for (int oi = 0; oi < 8; ++oi) {
        s16x4 wa = u2frag(w3k[(ob * 8 + oi) * 64 + lane]);
        #pragma unroll
        for (int m = 0; m < 4; ++m)
          acc3[ob][m] = __builtin_amdgcn_mfma_f32_16x16x16bf16_1k(
              wa, u2frag(pb[oi][m]), acc3[ob][m], 0, 0, 0);
      }
    __builtin_amdgcn_s_setprio(0);

    // ---- pool: in-register segmented reduce over up to 64 sorted columns ----
    // acc3[ob][m]: row(out-dim)=ob*16+quad*4+r, col(node)=l15+16m.
    {
      const int NT = has2 ? 64 : 32;
      int done = 0;
      while (done < NT) {                          // wave-uniform loop
        const int sel = done >> 4;
        int srcv = (sel & 2) ? ((sel & 1) ? cid3 : cid2)
                             : ((sel & 1) ? cid1 : cid0);
        const int g = __builtin_amdgcn_readlane(srcv, done & 15);
        const bool m0 = (cid0 == g), m1 = (cid1 == g), m2 = (cid2 == g), m3 = (cid3 == g);
        float red[4][4];
        #pragma unroll
        for (int ob = 0; ob < 4; ++ob)
          #pragma unroll
          for (int r = 0; r < 4; ++r)
            red[ob][r] = (m0 ? acc3[ob][0][r] : 0.f) + (m1 ? acc3[ob][1][r] : 0.f)
                       + (m2 ? acc3[ob][2][r] : 0.f) + (m3 ? acc3[ob][3][r] : 0.f);
        #pragma unroll
        for (int s = 1; s <= 8; s <<= 1)
          #pragma unroll
          for (int ob = 0; ob < 4; ++ob)
            #pragma unroll
            for (int r = 0; r < 4; ++r)
              red[ob][r] += __shfl_xor(red[ob][r], s, 64);
        const int cnt = (int)((__popcll(__ballot(m0)) + __popcll(__ballot(m1)) +
                               __popcll(__ballot(m2)) + __popcll(__ballot(m3))) >> 2);
        if (l15 == 0) {                            // 4 lanes (one per quad) fire atomics
          #pragma unroll
          for (int ob = 0; ob < 4; ++ob)
            #pragma unroll
            for (int r = 0; r < 4; ++r)
              atomicAdd(&gsum[g * OUTD + ob * 16 + quad * 4 + r], red[ob][r]);
        }
        if (lane == 0) atomicAdd(&gcnt[g], cnt);
        done += cnt;                               // cnt >= 1: column `done` matches g
      }
    }

    // ---- rotate the pipeline ----
    pair = npair;
    cid0 = nid0; cid1 = nid1; cid2 = nid2; cid3 = nid3;
    #pragma unroll
    for (int m = 0; m < 4; ++m) {
      cz[m] = nz[m]; cpx[m] = npx[m]; cpy[m] = npy[m]; cpz[m] = npz[m];
    }
  }
}

extern "C" __global__ void gnn_finalize(const float* __restrict__ gsum,
                                        const int* __restrict__ gcnt,
                                        const float* __restrict__ b3,
                                        float* __restrict__ out)
{
  int i = blockIdx.x * 256 + threadIdx.x;
  if (i < N_GRAPHS * OUTD) {
    int g = i >> 6, o = i & 63;
    int c = gcnt[g];
    out[i] = (c > 0) ? (gsum[i] / (float)c + b3[o]) : 0.f;
  }
}

extern "C" void kernel_launch(void* const* d_in, const int* in_sizes, int n_in,
                              void* d_out, int out_size, void* d_ws, size_t ws_size,
                              hipStream_t stream) {
  const float* pos  = (const float*)d_in[0];
  const int*   z    = (const int*)d_in[1];
  const int*   batch= (const int*)d_in[2];
  const float* emb  = (const float*)d_in[3];
  const float* W1   = (const float*)d_in[4];
  const float* b1   = (const float*)d_in[5];
  const float* W2   = (const float*)d_in[6];
  const float* b2   = (const float*)d_in[7];
  const float* W3   = (const float*)d_in[8];
  const float* b3   = (const float*)d_in[9];

  float* gsum = (float*)d_ws;
  int*   gcnt = (int*)((char*)d_ws + WS_GCNT);
  unsigned short* Tg = (unsigned short*)((char*)d_ws + WS_T);

  // prep also zeroes gsum/gcnt (memset dispatch folded in)
  hipLaunchKernelGGL(gnn_prep, dim3(256), dim3(HID), 0, stream,
                     emb, W1, b1, Tg, (f32x4*)d_ws);

  hipFuncSetAttribute((const void*)gnn_main,
                      hipFuncAttributeMaxDynamicSharedMemorySize, LDS_BYTES);
  hipLaunchKernelGGL(gnn_main, dim3(NBLOCKS), dim3(512), LDS_BYTES, stream,
                     pos, z, batch, Tg, W1, W2, b2, W3, gsum, gcnt);
  hipLaunchKernelGGL(gnn_finalize, dim3((N_GRAPHS * OUTD + 255) / 256), dim3(256), 0, stream,
                     gsum, gcnt, b3, (float*)d_out);
}